// Round 2
// baseline (170.558 us; speedup 1.0000x reference)
//
#include <hip/hip_runtime.h>
#include <math.h>

#define Bn 8
#define Nn 4096
#define Dn 256
#define En 65536
#define CAP 48

typedef __bf16 bf8 __attribute__((ext_vector_type(8)));
typedef float f4 __attribute__((ext_vector_type(4)));
typedef unsigned short us8 __attribute__((ext_vector_type(8)));

__device__ __forceinline__ float4 ld4(const float* p) { return *(const float4*)p; }

__device__ __forceinline__ unsigned short f2bf(float f) {
    union { float f; unsigned int u; } v; v.f = f;
    unsigned int r = v.u + 0x7fff + ((v.u >> 16) & 1);
    return (unsigned short)(r >> 16);
}
__device__ __forceinline__ float bf2f(unsigned short h) {
    union { unsigned int u; float f; } v; v.u = (unsigned int)h << 16;
    return v.f;
}

// ---------------- swizzled LDS tile helpers (verified r2-r6: conflicts == 0) ---------
// 16 rows x 32 bf16 per 1KB chunk; unit = row-pair (128B), 8 slots of 16B.
// slot s in unit u holds (r_local, kq) with ((r&1)<<2 | kq) = s ^ (u&7).

__device__ __forceinline__ void stage16c(const unsigned short* __restrict__ gchunk,
                                         int stride, char* ldschunk, int lane) {
    int u = lane >> 3, s = lane & 7;
    int xx = s ^ (u & 7);
    const unsigned short* g = gchunk + (size_t)(2 * u + (xx >> 2)) * stride + (xx & 3) * 8;
    __builtin_amdgcn_global_load_lds((const __attribute__((address_space(1))) void*)g,
                                     (__attribute__((address_space(3))) void*)ldschunk,
                                     16, 0, 0);
}

__device__ __forceinline__ bf8 fragld(const unsigned short* region, int r, int q) {
    int s = (((r & 1) << 2) | q) ^ ((r >> 1) & 7);
    return *(const bf8*)(region + (r >> 1) * 64 + s * 8);
}

__device__ __forceinline__ void ldswrite8(unsigned short* region, int r, int q,
                                          const unsigned short* vals) {
    int s = (((r & 1) << 2) | q) ^ ((r >> 1) & 7);
    *(us8*)(region + (r >> 1) * 64 + s * 8) = *(const us8*)vals;
}

// ---------------- fused setup kernel ----------------
// block 0            : rowscan (mask -> rowidx/rowcnt)
// blocks [1, 25)     : wf  (Ball[o][0:256] = bf16(Wih @ W^T))
// blocks [25, 217)   : cast_wb (Ball[o][256:512] = bf16(Whh))
// blocks [217, 2265) : bucket fill (valid edges -> bucket[(b,v)][pos])
// blocks [2265, 6361): zero out rows whose mask == 0

__device__ void rowscan_piece(const int* __restrict__ mask, int* __restrict__ rowidx,
                              int* __restrict__ rowcnt, int* part) {
    int t = threadIdx.x;
    int base = t * 128;
    unsigned long long b0 = 0, b1 = 0;
    int s = 0;
#pragma unroll 8
    for (int i = 0; i < 64; i++) {
        int m = mask[base + i] > 0;
        b0 |= (unsigned long long)m << i; s += m;
    }
#pragma unroll 8
    for (int i = 0; i < 64; i++) {
        int m = mask[base + 64 + i] > 0;
        b1 |= (unsigned long long)m << i; s += m;
    }
    part[t] = s;
    __syncthreads();
    for (int st = 1; st < 256; st <<= 1) {
        int v = (t >= st) ? part[t - st] : 0;
        __syncthreads();
        part[t] += v;
        __syncthreads();
    }
    int run = part[t] - s;
    for (int i = 0; i < 64; i++)
        if ((b0 >> i) & 1) rowidx[run++] = base + i;
    for (int i = 0; i < 64; i++)
        if ((b1 >> i) & 1) rowidx[run++] = base + 64 + i;
    if (t == 255) rowcnt[0] = part[255];
}

__device__ void wf_piece(int wfi, const float* __restrict__ Wih, const float* __restrict__ W,
                         unsigned short* __restrict__ Ball, unsigned short* lds) {
    int t = threadIdx.x, lane = t & 63, w = t >> 6;
    int wr = w >> 1, wc = w & 1, q = lane >> 4, c16 = lane & 15;
    int o0 = (wfi % 6) * 128, d0b = (wfi / 6) * 64;
    f4 acc[4][2];
    f4 zz = {0.f, 0.f, 0.f, 0.f};
#pragma unroll
    for (int rt = 0; rt < 4; rt++)
#pragma unroll
        for (int ct = 0; ct < 2; ct++) acc[rt][ct] = zz;

    int r = t >> 1, half = t & 1;
    for (int k0 = 0; k0 < 256; k0 += 32) {
        const float* pa = Wih + (size_t)(o0 + r) * 256 + k0 + half * 16;
        float4 a0 = ld4(pa), a1 = ld4(pa + 4), a2 = ld4(pa + 8), a3 = ld4(pa + 12);
        float4 b0, b1, b2, b3;
        if (t < 128) {
            const float* pb = W + (size_t)(d0b + r) * 256 + k0 + half * 16;
            b0 = ld4(pb); b1 = ld4(pb + 4); b2 = ld4(pb + 8); b3 = ld4(pb + 12);
        }
        __syncthreads();
        unsigned short tmp[16];
        tmp[0] = f2bf(a0.x); tmp[1] = f2bf(a0.y); tmp[2] = f2bf(a0.z); tmp[3] = f2bf(a0.w);
        tmp[4] = f2bf(a1.x); tmp[5] = f2bf(a1.y); tmp[6] = f2bf(a1.z); tmp[7] = f2bf(a1.w);
        tmp[8] = f2bf(a2.x); tmp[9] = f2bf(a2.y); tmp[10] = f2bf(a2.z); tmp[11] = f2bf(a2.w);
        tmp[12] = f2bf(a3.x); tmp[13] = f2bf(a3.y); tmp[14] = f2bf(a3.z); tmp[15] = f2bf(a3.w);
        ldswrite8(lds, r, half * 2, tmp);
        ldswrite8(lds, r, half * 2 + 1, tmp + 8);
        if (t < 128) {
            unsigned short tb[16];
            tb[0] = f2bf(b0.x); tb[1] = f2bf(b0.y); tb[2] = f2bf(b0.z); tb[3] = f2bf(b0.w);
            tb[4] = f2bf(b1.x); tb[5] = f2bf(b1.y); tb[6] = f2bf(b1.z); tb[7] = f2bf(b1.w);
            tb[8] = f2bf(b2.x); tb[9] = f2bf(b2.y); tb[10] = f2bf(b2.z); tb[11] = f2bf(b2.w);
            tb[12] = f2bf(b3.x); tb[13] = f2bf(b3.y); tb[14] = f2bf(b3.z); tb[15] = f2bf(b3.w);
            ldswrite8(lds + 4096, r, half * 2, tb);
            ldswrite8(lds + 4096, r, half * 2 + 1, tb + 8);
        }
        __syncthreads();
        bf8 a[4];
#pragma unroll
        for (int rt = 0; rt < 4; rt++) a[rt] = fragld(lds, wr * 64 + rt * 16 + c16, q);
#pragma unroll
        for (int ct = 0; ct < 2; ct++) {
            bf8 b = fragld(lds + 4096, wc * 32 + ct * 16 + c16, q);
#pragma unroll
            for (int rt = 0; rt < 4; rt++)
                acc[rt][ct] = __builtin_amdgcn_mfma_f32_16x16x32_bf16(a[rt], b, acc[rt][ct], 0, 0, 0);
        }
    }
#pragma unroll
    for (int ct = 0; ct < 2; ct++) {
        int col = d0b + wc * 32 + ct * 16 + c16;
#pragma unroll
        for (int rt = 0; rt < 4; rt++) {
            int ob = o0 + wr * 64 + rt * 16 + q * 4;
#pragma unroll
            for (int i = 0; i < 4; i++)
                Ball[(size_t)(ob + i) * 512 + col] = f2bf(acc[rt][ct][i]);
        }
    }
}

__global__ __launch_bounds__(256) void setup_kernel(const int* __restrict__ ei,
                                                    const int* __restrict__ mask,
                                                    const float* __restrict__ Wih,
                                                    const float* __restrict__ W,
                                                    const float* __restrict__ Whh,
                                                    const float* __restrict__ ew,
                                                    int* __restrict__ cnt,
                                                    int2* __restrict__ bucket,
                                                    int* __restrict__ rowidx,
                                                    int* __restrict__ rowcnt,
                                                    unsigned short* __restrict__ Ball,
                                                    float* __restrict__ out) {
    __shared__ __align__(16) unsigned short lds[6144];   // wf scratch (also part[] alias)
    int b = blockIdx.x, t = threadIdx.x;
    if (b == 0) {
        rowscan_piece(mask, rowidx, rowcnt, (int*)lds);
        return;
    }
    if (b < 25) {
        wf_piece(b - 1, Wih, W, Ball, lds);
        return;
    }
    if (b < 217) {
        int i = ((b - 25) * 256 + t) * 4;
        float4 wv = ld4(Whh + i);
        int o = i >> 8, d = i & 255;
        ushort4 ov;
        ov.x = f2bf(wv.x); ov.y = f2bf(wv.y); ov.z = f2bf(wv.z); ov.w = f2bf(wv.w);
        *(ushort4*)(Ball + (size_t)o * 512 + 256 + d) = ov;
        return;
    }
    if (b < 2265) {   // bucket fill
        int idx = (b - 217) * 256 + t;        // [0, B*E)
        int bb = idx >> 16, e = idx & 65535;
        const int* eb = ei + (size_t)bb * 2 * En;
        int u = eb[e];
        int v = eb[En + e];
        const int* mb = mask + bb * Nn;
        if (mb[u] > 0 && mb[v] > 0) {
            int pos = atomicAdd(&cnt[bb * Nn + v], 1);
            if (pos < CAP) {
                int2 pr;
                pr.x = u;
                pr.y = __float_as_int(ew[(size_t)bb * En + e]);
                bucket[(size_t)(bb * Nn + v) * CAP + pos] = pr;
            }
        }
        return;
    }
    {   // zero out rows whose mask == 0
        int zb = b - 2265;                    // [0, 4096): 8 rows each
        int r = zb * 8 + (t >> 5);
        if (mask[r] > 0) return;              // gru will write this row
        int col = (t & 31) * 8;
        float4 z = make_float4(0.f, 0.f, 0.f, 0.f);
        *(float4*)(out + (size_t)r * 256 + col) = z;
        *(float4*)(out + (size_t)r * 256 + col + 4) = z;
    }
}

// ---------------- Ac[i] = [ pre_agg(v) | x(v) ]  (compacted rows, bf16) -------------
// Gathers fp32 x rows (1KB); 8 gathers in flight (tail predicated by zero wt).
// x[v] load issued FIRST so its latency overlaps the bucket->u->x dependent chain.

__global__ __launch_bounds__(256) void agg_kernel(const float* __restrict__ x,
                                                  const int* __restrict__ cnt,
                                                  const int2* __restrict__ bucket,
                                                  const int* __restrict__ rowidx,
                                                  const int* __restrict__ rowcnt,
                                                  unsigned short* __restrict__ Ac) {
    int wave = threadIdx.x >> 6, lane = threadIdx.x & 63;
    int i = blockIdx.x * 4 + wave;
    if (i >= rowcnt[0]) return;
    int v = rowidx[i];
    int b = v >> 12, n = v & 4095;
    float4 xv = ld4(x + (size_t)v * 256 + lane * 4);   // independent: issue early
    int m = cnt[b * Nn + n];
    m = m < CAP ? m : CAP;
    const int2* bk = bucket + (size_t)(b * Nn + n) * CAP;
    const float* Xb = x + (size_t)b * Nn * 256;
    float a0 = 0.f, a1 = 0.f, a2 = 0.f, a3 = 0.f;
    for (int j = 0; j < m; j += 8) {
        int u[8]; float wv[8];
#pragma unroll
        for (int k = 0; k < 8; k++) {
            int jj = j + k;
            bool ok = jj < m;
            int2 pr = bk[ok ? jj : 0];
            u[k] = pr.x;
            wv[k] = ok ? __int_as_float(pr.y) : 0.f;
        }
        float4 mv[8];
#pragma unroll
        for (int k = 0; k < 8; k++) mv[k] = ld4(Xb + (size_t)u[k] * 256 + lane * 4);
#pragma unroll
        for (int k = 0; k < 8; k++) {
            a0 += wv[k] * mv[k].x; a1 += wv[k] * mv[k].y;
            a2 += wv[k] * mv[k].z; a3 += wv[k] * mv[k].w;
        }
    }
    ushort4 o;
    o.x = f2bf(a0); o.y = f2bf(a1); o.z = f2bf(a2); o.w = f2bf(a3);
    *(ushort4*)(Ac + (size_t)i * 512 + lane * 4) = o;
    ushort4 xo;
    xo.x = f2bf(xv.x); xo.y = f2bf(xv.y); xo.z = f2bf(xv.z); xo.w = f2bf(xv.w);
    *(ushort4*)(Ac + (size_t)i * 512 + 256 + lane * 4) = xo;
}

// ---------------- fused GRU over compacted rows (64x64 tile, high-TLP pipeline) -----
// Block: 64 rows x 64 dims x 3 gates; 256 threads = 4 waves (2 row-grp x 2 col-grp),
// wave = 32r x 32c; BK=32, 16 steps. LDS 2 x 16KB: A chunks 0..3 (rows c*16),
// B chunks 4..15 (gate g=(c-4)>>2, colgrp cg=(c-4)&3). Each wave stages exactly
// 4 chunks/step -> uniform counted vmcnt(4). 32KB LDS => 5 blocks/CU resident;
// with rowcnt~16K there are ~1024 active blocks = 4/CU, so cross-block TLP hides
// the stage latency the in-block depth-1 pipeline doesn't (m114 mechanism).

#define GRU_STAGE(kk, bufbase)                                                      \
    {                                                                               \
        _Pragma("unroll") for (int j = 0; j < 4; j++) {                             \
            int c = w * 4 + j;                                                      \
            const unsigned short* src;                                              \
            if (c < 4)                                                              \
                src = Ac + (size_t)(row0 + c * 16) * 512 + (kk) * 32;               \
            else {                                                                  \
                int g = (c - 4) >> 2, cg = (c - 4) & 3;                             \
                src = Ball + (size_t)(g * 256 + d0 + cg * 16) * 512 + (kk) * 32;    \
            }                                                                       \
            stage16c(src, 512, (char*)(bufbase) + c * 1024, lane);                  \
        }                                                                           \
    }

#define GRU_COMPUTE(bufbase, ACCM)                                                  \
    {                                                                               \
        const unsigned short* rb = (bufbase);                                       \
        bf8 a0 = fragld(rb + (wr * 2) * 512, c16, q);                               \
        bf8 a1 = fragld(rb + (wr * 2 + 1) * 512, c16, q);                           \
        _Pragma("unroll") for (int ct = 0; ct < 2; ct++) {                          \
            int cg = wc * 2 + ct;                                                   \
            bf8 br = fragld(rb + (4 + cg) * 512, c16, q);                           \
            bf8 bz = fragld(rb + (8 + cg) * 512, c16, q);                           \
            bf8 bm = fragld(rb + (12 + cg) * 512, c16, q);                          \
            acc_r[0][ct] = __builtin_amdgcn_mfma_f32_16x16x32_bf16(a0, br, acc_r[0][ct], 0, 0, 0); \
            acc_r[1][ct] = __builtin_amdgcn_mfma_f32_16x16x32_bf16(a1, br, acc_r[1][ct], 0, 0, 0); \
            acc_z[0][ct] = __builtin_amdgcn_mfma_f32_16x16x32_bf16(a0, bz, acc_z[0][ct], 0, 0, 0); \
            acc_z[1][ct] = __builtin_amdgcn_mfma_f32_16x16x32_bf16(a1, bz, acc_z[1][ct], 0, 0, 0); \
            ACCM[0][ct] = __builtin_amdgcn_mfma_f32_16x16x32_bf16(a0, bm, ACCM[0][ct], 0, 0, 0);   \
            ACCM[1][ct] = __builtin_amdgcn_mfma_f32_16x16x32_bf16(a1, bm, ACCM[1][ct], 0, 0, 0);   \
        }                                                                           \
    }

__global__ __launch_bounds__(256, 5) void gru_kernel(const unsigned short* __restrict__ Ac,
                                                     const unsigned short* __restrict__ Ball,
                                                     const float* __restrict__ bih,
                                                     const float* __restrict__ bhh,
                                                     const int* __restrict__ rowidx,
                                                     const int* __restrict__ rowcnt,
                                                     float* __restrict__ out) {
    __shared__ __align__(16) unsigned short lds[16384];   // 2 x 16KB
    const int t = threadIdx.x;
    const int lane = t & 63, w = t >> 6;
    const int wr = w >> 1, wc = w & 1;
    const int q = lane >> 4, c16 = lane & 15;
    const int row0 = blockIdx.x * 64, d0 = blockIdx.y * 64;
    const int cnt = rowcnt[0];
    if (row0 >= cnt) return;   // uniform, before any barrier

    f4 acc_r[2][2], acc_z[2][2], acc_gn[2][2], acc_hn[2][2];
    f4 zz = {0.f, 0.f, 0.f, 0.f};
#pragma unroll
    for (int rt = 0; rt < 2; rt++)
#pragma unroll
        for (int ct = 0; ct < 2; ct++) {
            acc_r[rt][ct] = zz; acc_z[rt][ct] = zz;
            acc_gn[rt][ct] = zz; acc_hn[rt][ct] = zz;
        }

    unsigned short* buf0 = lds;
    unsigned short* buf1 = lds + 8192;

    GRU_STAGE(0, buf0)
#pragma unroll
    for (int kk = 0; kk < 16; kk++) {
        unsigned short* sbuf = (kk & 1) ? buf0 : buf1;   // stage target for kk+1
        unsigned short* cbuf = (kk & 1) ? buf1 : buf0;   // compute source for kk
        __builtin_amdgcn_s_barrier();                    // sbuf free to overwrite
        if (kk < 15) {
            GRU_STAGE(kk + 1, sbuf)
            asm volatile("s_waitcnt vmcnt(4)" ::: "memory");   // step-kk chunks landed
        } else {
            asm volatile("s_waitcnt vmcnt(0)" ::: "memory");
        }
        __builtin_amdgcn_sched_barrier(0);
        __builtin_amdgcn_s_barrier();                    // everyone's step-kk in LDS
        __builtin_amdgcn_sched_barrier(0);
        __builtin_amdgcn_s_setprio(1);
        if (kk < 8) { GRU_COMPUTE(cbuf, acc_gn) }
        else        { GRU_COMPUTE(cbuf, acc_hn) }
        __builtin_amdgcn_s_setprio(0);
        __builtin_amdgcn_sched_barrier(0);
    }

#pragma unroll
    for (int ct = 0; ct < 2; ct++) {
        int dd = d0 + wc * 32 + ct * 16 + c16;
        float b_r = bih[dd] + bhh[dd];
        float b_z = bih[dd + 256] + bhh[dd + 256];
        float b_gn = bih[dd + 512];
        float b_hn = bhh[dd + 512];
#pragma unroll
        for (int rt = 0; rt < 2; rt++) {
            int rbase = row0 + wr * 32 + rt * 16 + q * 4;
#pragma unroll
            for (int i = 0; i < 4; i++) {
                int rc = rbase + i;
                if (rc < cnt) {
                    float sr = acc_r[rt][ct][i] + b_r;
                    float sz = acc_z[rt][ct][i] + b_z;
                    float gn = acc_gn[rt][ct][i] + b_gn;
                    float hn = acc_hn[rt][ct][i] + b_hn;
                    float rg = 1.f / (1.f + __expf(-sr));
                    float zg = 1.f / (1.f + __expf(-sz));
                    float pre = gn + rg * hn;
                    float e2 = __expf(2.f * pre);
                    float ng = 1.f - 2.f / (e2 + 1.f);   // tanh(pre)
                    float xv = bf2f(Ac[(size_t)rc * 512 + 256 + dd]);
                    float h = (1.f - zg) * ng + zg * xv;
                    int v = rowidx[rc];
                    out[(size_t)v * 256 + dd] = h;
                }
            }
        }
    }
}

// ---------------- launch ----------------

extern "C" void kernel_launch(void* const* d_in, const int* in_sizes, int n_in,
                              void* d_out, int out_size, void* d_ws, size_t ws_size,
                              hipStream_t stream) {
    const float* x   = (const float*)d_in[0];
    const int*   ei  = (const int*)d_in[1];
    const float* ew  = (const float*)d_in[2];
    const int*   msk = (const int*)d_in[3];
    const float* W   = (const float*)d_in[4];
    const float* Wih = (const float*)d_in[5];
    const float* Whh = (const float*)d_in[6];
    const float* bih = (const float*)d_in[7];
    const float* bhh = (const float*)d_in[8];
    float* out = (float*)d_out;

    char* p = (char*)d_ws;
    unsigned short* Ac   = (unsigned short*)p; p += (size_t)Bn * Nn * 512 * 2;   // 32 MB
    unsigned short* Ball = (unsigned short*)p; p += (size_t)768 * 512 * 2;       // 768 KB
    int2* bucket = (int2*)p;  p += (size_t)Bn * Nn * CAP * sizeof(int2);         // 12.6 MB
    int* cnt    = (int*)p;    p += (size_t)Bn * Nn * sizeof(int);
    int* rowidx = (int*)p;    p += (size_t)Bn * Nn * sizeof(int);
    int* rowcnt = (int*)p;    p += 128;

    hipMemsetAsync(cnt, 0, (size_t)Bn * Nn * sizeof(int), stream);
    setup_kernel<<<6361, 256, 0, stream>>>(ei, msk, Wih, W, Whh, ew, cnt, bucket,
                                           rowidx, rowcnt, Ball, out);
    agg_kernel<<<(Bn * Nn) / 4, 256, 0, stream>>>(x, cnt, bucket, rowidx, rowcnt, Ac);
    gru_kernel<<<dim3(512, 4), 256, 0, stream>>>(Ac, Ball, bih, bhh, rowidx, rowcnt, out);
}

// Round 3
// 160.708 us; speedup vs baseline: 1.0613x; 1.0613x over previous
//
#include <hip/hip_runtime.h>
#include <math.h>

#define Bn 8
#define Nn 4096
#define Dn 256
#define En 65536
#define CAP 48

typedef __bf16 bf8 __attribute__((ext_vector_type(8)));
typedef float f4 __attribute__((ext_vector_type(4)));
typedef unsigned short us8 __attribute__((ext_vector_type(8)));

__device__ __forceinline__ float4 ld4(const float* p) { return *(const float4*)p; }

__device__ __forceinline__ unsigned short f2bf(float f) {
    union { float f; unsigned int u; } v; v.f = f;
    unsigned int r = v.u + 0x7fff + ((v.u >> 16) & 1);
    return (unsigned short)(r >> 16);
}
__device__ __forceinline__ float bf2f(unsigned short h) {
    union { unsigned int u; float f; } v; v.u = (unsigned int)h << 16;
    return v.f;
}

// ---------------- swizzled LDS tile helpers (verified r2-r6: conflicts == 0) ---------
// 16 rows x 32 bf16 per 1KB chunk; unit = row-pair (128B), 8 slots of 16B.
// slot s in unit u holds (r_local, kq) with ((r&1)<<2 | kq) = s ^ (u&7).

__device__ __forceinline__ void stage16c(const unsigned short* __restrict__ gchunk,
                                         int stride, char* ldschunk, int lane) {
    int u = lane >> 3, s = lane & 7;
    int xx = s ^ (u & 7);
    const unsigned short* g = gchunk + (size_t)(2 * u + (xx >> 2)) * stride + (xx & 3) * 8;
    __builtin_amdgcn_global_load_lds((const __attribute__((address_space(1))) void*)g,
                                     (__attribute__((address_space(3))) void*)ldschunk,
                                     16, 0, 0);
}

__device__ __forceinline__ bf8 fragld(const unsigned short* region, int r, int q) {
    int s = (((r & 1) << 2) | q) ^ ((r >> 1) & 7);
    return *(const bf8*)(region + (r >> 1) * 64 + s * 8);
}

__device__ __forceinline__ void ldswrite8(unsigned short* region, int r, int q,
                                          const unsigned short* vals) {
    int s = (((r & 1) << 2) | q) ^ ((r >> 1) & 7);
    *(us8*)(region + (r >> 1) * 64 + s * 8) = *(const us8*)vals;
}

// ---------------- fused setup kernel ----------------
// block 0            : rowscan (mask -> rowidx/rowcnt + per-batch prefix ends)
// blocks [1, 25)     : wf  (Ball[o][0:256] = bf16(Wih @ W^T))
// blocks [25, 217)   : cast_wb (Ball[o][256:512] = bf16(Whh))
// blocks [217, 2265) : bucket fill (valid edges -> bucket[(b,v)][pos])
// blocks [2265, 6361): zero out rows whose mask == 0

__device__ void rowscan_piece(const int* __restrict__ mask, int* __restrict__ rowidx,
                              int* __restrict__ rowcnt, int* part) {
    int t = threadIdx.x;
    int base = t * 128;
    unsigned long long b0 = 0, b1 = 0;
    int s = 0;
#pragma unroll 8
    for (int i = 0; i < 64; i++) {
        int m = mask[base + i] > 0;
        b0 |= (unsigned long long)m << i; s += m;
    }
#pragma unroll 8
    for (int i = 0; i < 64; i++) {
        int m = mask[base + 64 + i] > 0;
        b1 |= (unsigned long long)m << i; s += m;
    }
    part[t] = s;
    __syncthreads();
    for (int st = 1; st < 256; st <<= 1) {
        int v = (t >= st) ? part[t - st] : 0;
        __syncthreads();
        part[t] += v;
        __syncthreads();
    }
    int run = part[t] - s;
    for (int i = 0; i < 64; i++)
        if ((b0 >> i) & 1) rowidx[run++] = base + i;
    for (int i = 0; i < 64; i++)
        if ((b1 >> i) & 1) rowidx[run++] = base + 64 + i;
    // per-batch prefix ends: batch b = nodes [b*4096,(b+1)*4096) = t in [b*32,(b+1)*32)
    if ((t & 31) == 31) rowcnt[1 + (t >> 5)] = part[t];
    if (t == 255) rowcnt[0] = part[255];
}

__device__ void wf_piece(int wfi, const float* __restrict__ Wih, const float* __restrict__ W,
                         unsigned short* __restrict__ Ball, unsigned short* lds) {
    int t = threadIdx.x, lane = t & 63, w = t >> 6;
    int wr = w >> 1, wc = w & 1, q = lane >> 4, c16 = lane & 15;
    int o0 = (wfi % 6) * 128, d0b = (wfi / 6) * 64;
    f4 acc[4][2];
    f4 zz = {0.f, 0.f, 0.f, 0.f};
#pragma unroll
    for (int rt = 0; rt < 4; rt++)
#pragma unroll
        for (int ct = 0; ct < 2; ct++) acc[rt][ct] = zz;

    int r = t >> 1, half = t & 1;
    for (int k0 = 0; k0 < 256; k0 += 32) {
        const float* pa = Wih + (size_t)(o0 + r) * 256 + k0 + half * 16;
        float4 a0 = ld4(pa), a1 = ld4(pa + 4), a2 = ld4(pa + 8), a3 = ld4(pa + 12);
        float4 b0, b1, b2, b3;
        if (t < 128) {
            const float* pb = W + (size_t)(d0b + r) * 256 + k0 + half * 16;
            b0 = ld4(pb); b1 = ld4(pb + 4); b2 = ld4(pb + 8); b3 = ld4(pb + 12);
        }
        __syncthreads();
        unsigned short tmp[16];
        tmp[0] = f2bf(a0.x); tmp[1] = f2bf(a0.y); tmp[2] = f2bf(a0.z); tmp[3] = f2bf(a0.w);
        tmp[4] = f2bf(a1.x); tmp[5] = f2bf(a1.y); tmp[6] = f2bf(a1.z); tmp[7] = f2bf(a1.w);
        tmp[8] = f2bf(a2.x); tmp[9] = f2bf(a2.y); tmp[10] = f2bf(a2.z); tmp[11] = f2bf(a2.w);
        tmp[12] = f2bf(a3.x); tmp[13] = f2bf(a3.y); tmp[14] = f2bf(a3.z); tmp[15] = f2bf(a3.w);
        ldswrite8(lds, r, half * 2, tmp);
        ldswrite8(lds, r, half * 2 + 1, tmp + 8);
        if (t < 128) {
            unsigned short tb[16];
            tb[0] = f2bf(b0.x); tb[1] = f2bf(b0.y); tb[2] = f2bf(b0.z); tb[3] = f2bf(b0.w);
            tb[4] = f2bf(b1.x); tb[5] = f2bf(b1.y); tb[6] = f2bf(b1.z); tb[7] = f2bf(b1.w);
            tb[8] = f2bf(b2.x); tb[9] = f2bf(b2.y); tb[10] = f2bf(b2.z); tb[11] = f2bf(b2.w);
            tb[12] = f2bf(b3.x); tb[13] = f2bf(b3.y); tb[14] = f2bf(b3.z); tb[15] = f2bf(b3.w);
            ldswrite8(lds + 4096, r, half * 2, tb);
            ldswrite8(lds + 4096, r, half * 2 + 1, tb + 8);
        }
        __syncthreads();
        bf8 a[4];
#pragma unroll
        for (int rt = 0; rt < 4; rt++) a[rt] = fragld(lds, wr * 64 + rt * 16 + c16, q);
#pragma unroll
        for (int ct = 0; ct < 2; ct++) {
            bf8 b = fragld(lds + 4096, wc * 32 + ct * 16 + c16, q);
#pragma unroll
            for (int rt = 0; rt < 4; rt++)
                acc[rt][ct] = __builtin_amdgcn_mfma_f32_16x16x32_bf16(a[rt], b, acc[rt][ct], 0, 0, 0);
        }
    }
#pragma unroll
    for (int ct = 0; ct < 2; ct++) {
        int col = d0b + wc * 32 + ct * 16 + c16;
#pragma unroll
        for (int rt = 0; rt < 4; rt++) {
            int ob = o0 + wr * 64 + rt * 16 + q * 4;
#pragma unroll
            for (int i = 0; i < 4; i++)
                Ball[(size_t)(ob + i) * 512 + col] = f2bf(acc[rt][ct][i]);
        }
    }
}

__global__ __launch_bounds__(256) void setup_kernel(const int* __restrict__ ei,
                                                    const int* __restrict__ mask,
                                                    const float* __restrict__ Wih,
                                                    const float* __restrict__ W,
                                                    const float* __restrict__ Whh,
                                                    const float* __restrict__ ew,
                                                    int* __restrict__ cnt,
                                                    int2* __restrict__ bucket,
                                                    int* __restrict__ rowidx,
                                                    int* __restrict__ rowcnt,
                                                    unsigned short* __restrict__ Ball,
                                                    float* __restrict__ out) {
    __shared__ __align__(16) unsigned short lds[6144];   // wf scratch (also part[] alias)
    int b = blockIdx.x, t = threadIdx.x;
    if (b == 0) {
        rowscan_piece(mask, rowidx, rowcnt, (int*)lds);
        return;
    }
    if (b < 25) {
        wf_piece(b - 1, Wih, W, Ball, lds);
        return;
    }
    if (b < 217) {
        int i = ((b - 25) * 256 + t) * 4;
        float4 wv = ld4(Whh + i);
        int o = i >> 8, d = i & 255;
        ushort4 ov;
        ov.x = f2bf(wv.x); ov.y = f2bf(wv.y); ov.z = f2bf(wv.z); ov.w = f2bf(wv.w);
        *(ushort4*)(Ball + (size_t)o * 512 + 256 + d) = ov;
        return;
    }
    if (b < 2265) {   // bucket fill
        int idx = (b - 217) * 256 + t;        // [0, B*E)
        int bb = idx >> 16, e = idx & 65535;
        const int* eb = ei + (size_t)bb * 2 * En;
        int u = eb[e];
        int v = eb[En + e];
        const int* mb = mask + bb * Nn;
        if (mb[u] > 0 && mb[v] > 0) {
            int pos = atomicAdd(&cnt[bb * Nn + v], 1);
            if (pos < CAP) {
                int2 pr;
                pr.x = u;
                pr.y = __float_as_int(ew[(size_t)bb * En + e]);
                bucket[(size_t)(bb * Nn + v) * CAP + pos] = pr;
            }
        }
        return;
    }
    {   // zero out rows whose mask == 0
        int zb = b - 2265;                    // [0, 4096): 8 rows each
        int r = zb * 8 + (t >> 5);
        if (mask[r] > 0) return;              // gru will write this row
        int col = (t & 31) * 8;
        float4 z = make_float4(0.f, 0.f, 0.f, 0.f);
        *(float4*)(out + (size_t)r * 256 + col) = z;
        *(float4*)(out + (size_t)r * 256 + col + 4) = z;
    }
}

// ---------------- Ac[i] = [ pre_agg(v) | x(v) ]  (compacted rows, bf16) -------------
// XCD-batch affinity: block j handles batch j%8 -> under round-robin dispatch each
// XCD's x-gathers hit only x_b (4MB = one XCD L2). Stride loop guards batch overflow.

__global__ __launch_bounds__(256) void agg_kernel(const float* __restrict__ x,
                                                  const int* __restrict__ cnt,
                                                  const int2* __restrict__ bucket,
                                                  const int* __restrict__ rowidx,
                                                  const int* __restrict__ rowcnt,
                                                  unsigned short* __restrict__ Ac) {
    int wave = threadIdx.x >> 6, lane = threadIdx.x & 63;
    int b = blockIdx.x & 7;
    int slot = blockIdx.x >> 3;
    int p0 = (b == 0) ? 0 : rowcnt[b];     // rowcnt[b] = end of batch b-1
    int p1 = rowcnt[b + 1];
    const int2* bkb = bucket + (size_t)b * Nn * CAP;
    const int* cntb = cnt + b * Nn;
    const float* Xb = x + (size_t)b * Nn * 256;
    for (int i = p0 + slot * 4 + wave; i < p1; i += 4 * 512) {
        int v = rowidx[i];
        int n = v & 4095;
        float4 xv = ld4(Xb + (size_t)n * 256 + lane * 4);   // independent: issue early
        int m = cntb[n];
        m = m < CAP ? m : CAP;
        const int2* bk = bkb + (size_t)n * CAP;
        float a0 = 0.f, a1 = 0.f, a2 = 0.f, a3 = 0.f;
        for (int j = 0; j < m; j += 8) {
            int u[8]; float wv[8];
#pragma unroll
            for (int k = 0; k < 8; k++) {
                int jj = j + k;
                bool ok = jj < m;
                int2 pr = bk[ok ? jj : 0];
                u[k] = pr.x;
                wv[k] = ok ? __int_as_float(pr.y) : 0.f;
            }
            float4 mv[8];
#pragma unroll
            for (int k = 0; k < 8; k++) mv[k] = ld4(Xb + (size_t)u[k] * 256 + lane * 4);
#pragma unroll
            for (int k = 0; k < 8; k++) {
                a0 += wv[k] * mv[k].x; a1 += wv[k] * mv[k].y;
                a2 += wv[k] * mv[k].z; a3 += wv[k] * mv[k].w;
            }
        }
        ushort4 o;
        o.x = f2bf(a0); o.y = f2bf(a1); o.z = f2bf(a2); o.w = f2bf(a3);
        *(ushort4*)(Ac + (size_t)i * 512 + lane * 4) = o;
        ushort4 xo;
        xo.x = f2bf(xv.x); xo.y = f2bf(xv.y); xo.z = f2bf(xv.z); xo.w = f2bf(xv.w);
        *(ushort4*)(Ac + (size_t)i * 512 + 256 + lane * 4) = xo;
    }
}

// ---------------- fused GRU over compacted rows (128x32 tile, depth-2 pipeline) -----
// Block: 128 rows x 32 dims x 3 gates; 512 threads = 8 waves (4 row-grp x 2 col-grp),
// wave = 32r x 16c; BK=32, 16 steps. LDS ring 3 x 14KB: A chunks 0..7 (rows c*16),
// B chunks 8..13 (gate g=(c-8)>>1, half h=(c-8)&1 of the 32-dim slice).
// waves 0-5 stage 2 chunks/step -> vmcnt(4) keeps stages k+1,k+2 in flight;
// waves 6-7 stage 1 -> vmcnt(2). 42KB LDS -> 3 blocks/CU = 24 waves/CU (was 16).
// XCD swizzle (m204 bijection over active blocks): each XCD owns a contiguous
// ~2048-row slice; gridDim.x=256 == 0 mod 8 so all 8 d-slices of a row-block land
// on the same XCD -> Ac slice (~2MB) + Ball (768KB) L2-resident.

#define GRU_STAGE(kk, bufbase)                                                      \
    {                                                                               \
        if (w < 6) {                                                                \
            _Pragma("unroll") for (int j = 0; j < 2; j++) {                         \
                int c = w * 2 + j;                                                  \
                const unsigned short* src;                                          \
                if (c < 8)                                                          \
                    src = Ac + (size_t)(row0 + c * 16) * 512 + (kk) * 32;           \
                else {                                                              \
                    int idx = c - 8, g = idx >> 1, h = idx & 1;                     \
                    src = Ball + (size_t)(g * 256 + d0 + h * 16) * 512 + (kk) * 32; \
                }                                                                   \
                stage16c(src, 512, (char*)(bufbase) + c * 1024, lane);              \
            }                                                                       \
        } else {                                                                    \
            int c = 12 + (w - 6);                                                   \
            int idx = c - 8, g = idx >> 1, h = idx & 1;                             \
            const unsigned short* src =                                             \
                Ball + (size_t)(g * 256 + d0 + h * 16) * 512 + (kk) * 32;           \
            stage16c(src, 512, (char*)(bufbase) + c * 1024, lane);                  \
        }                                                                           \
    }

#define GRU_COMPUTE(bufbase, ACCM)                                                  \
    {                                                                               \
        const unsigned short* rb = (bufbase);                                       \
        bf8 a0 = fragld(rb + (wr * 2) * 512, c16, q);                               \
        bf8 a1 = fragld(rb + (wr * 2 + 1) * 512, c16, q);                           \
        bf8 br = fragld(rb + (8 + wc) * 512, c16, q);                               \
        bf8 bz = fragld(rb + (10 + wc) * 512, c16, q);                              \
        bf8 bm = fragld(rb + (12 + wc) * 512, c16, q);                              \
        acc_r[0] = __builtin_amdgcn_mfma_f32_16x16x32_bf16(a0, br, acc_r[0], 0, 0, 0); \
        acc_r[1] = __builtin_amdgcn_mfma_f32_16x16x32_bf16(a1, br, acc_r[1], 0, 0, 0); \
        acc_z[0] = __builtin_amdgcn_mfma_f32_16x16x32_bf16(a0, bz, acc_z[0], 0, 0, 0); \
        acc_z[1] = __builtin_amdgcn_mfma_f32_16x16x32_bf16(a1, bz, acc_z[1], 0, 0, 0); \
        ACCM[0] = __builtin_amdgcn_mfma_f32_16x16x32_bf16(a0, bm, ACCM[0], 0, 0, 0);   \
        ACCM[1] = __builtin_amdgcn_mfma_f32_16x16x32_bf16(a1, bm, ACCM[1], 0, 0, 0);   \
    }

#define GRU_WAITV(n05, n67)                                                         \
    if (w < 6) { asm volatile("s_waitcnt vmcnt(" #n05 ")" ::: "memory"); }          \
    else       { asm volatile("s_waitcnt vmcnt(" #n67 ")" ::: "memory"); }          \
    __builtin_amdgcn_sched_barrier(0);

#define GRU_STEP(kk, STAGEBUF, COMPBUF, ACCM)                                       \
    __builtin_amdgcn_s_barrier();          /* (k+2)%3 buffer free to overwrite */   \
    GRU_STAGE((kk) + 2, STAGEBUF)                                                   \
    GRU_WAITV(4, 2)                        /* own stage(k) chunks landed */         \
    __builtin_amdgcn_s_barrier();          /* everyone's stage(k) landed */         \
    __builtin_amdgcn_s_setprio(1);                                                  \
    GRU_COMPUTE(COMPBUF, ACCM)                                                      \
    __builtin_amdgcn_s_setprio(0);                                                  \
    __builtin_amdgcn_sched_barrier(0);

#define GRU_STEP_LAST(kk, COMPBUF, ACCM, n05, n67)                                  \
    __builtin_amdgcn_s_barrier();                                                   \
    GRU_WAITV(n05, n67)                                                             \
    __builtin_amdgcn_s_barrier();                                                   \
    __builtin_amdgcn_s_setprio(1);                                                  \
    GRU_COMPUTE(COMPBUF, ACCM)                                                      \
    __builtin_amdgcn_s_setprio(0);                                                  \
    __builtin_amdgcn_sched_barrier(0);

__global__ __launch_bounds__(512, 6) void gru_kernel(const unsigned short* __restrict__ Ac,
                                                     const unsigned short* __restrict__ Ball,
                                                     const float* __restrict__ bih,
                                                     const float* __restrict__ bhh,
                                                     const int* __restrict__ rowidx,
                                                     const int* __restrict__ rowcnt,
                                                     float* __restrict__ out) {
    __shared__ __align__(16) unsigned short lds[21504];   // 3 x 14KB ring
    const int t = threadIdx.x;
    const int lane = t & 63, w = t >> 6;
    const int wr = w >> 1, wc = w & 1;
    const int q = lane >> 4, c16 = lane & 15;
    const int cnt = rowcnt[0];
    const int nact = (cnt + 127) >> 7;
    if (blockIdx.x >= nact) return;        // uniform, before any barrier
    // m204 bijective XCD remap over active blocks
    int q8 = nact >> 3, r8 = nact & 7;
    int xcd = blockIdx.x & 7, jj = blockIdx.x >> 3;
    int xp = (xcd < r8 ? xcd * (q8 + 1) : r8 * (q8 + 1) + (xcd - r8) * q8) + jj;
    const int row0 = xp * 128, d0 = blockIdx.y * 32;

    f4 acc_r[2], acc_z[2], acc_gn[2], acc_hn[2];
    f4 zz = {0.f, 0.f, 0.f, 0.f};
#pragma unroll
    for (int rt = 0; rt < 2; rt++) {
        acc_r[rt] = zz; acc_z[rt] = zz;
        acc_gn[rt] = zz; acc_hn[rt] = zz;
    }

    unsigned short* bufA = lds;
    unsigned short* bufB = lds + 7168;
    unsigned short* bufC = lds + 14336;

    // prologue: 2 stages in flight before first compute
    GRU_STAGE(0, bufA)
    GRU_STAGE(1, bufB)

    GRU_STEP(0,  bufC, bufA, acc_gn)
    GRU_STEP(1,  bufA, bufB, acc_gn)
    GRU_STEP(2,  bufB, bufC, acc_gn)
    GRU_STEP(3,  bufC, bufA, acc_gn)
    GRU_STEP(4,  bufA, bufB, acc_gn)
    GRU_STEP(5,  bufB, bufC, acc_gn)
    GRU_STEP(6,  bufC, bufA, acc_gn)
    GRU_STEP(7,  bufA, bufB, acc_gn)
    GRU_STEP(8,  bufB, bufC, acc_hn)
    GRU_STEP(9,  bufC, bufA, acc_hn)
    GRU_STEP(10, bufA, bufB, acc_hn)
    GRU_STEP(11, bufB, bufC, acc_hn)
    GRU_STEP(12, bufC, bufA, acc_hn)
    GRU_STEP(13, bufA, bufB, acc_hn)
    GRU_STEP_LAST(14, bufC, acc_hn, 2, 1)
    GRU_STEP_LAST(15, bufA, acc_hn, 0, 0)

    {
        int dd = d0 + wc * 16 + c16;
        float b_r = bih[dd] + bhh[dd];
        float b_z = bih[dd + 256] + bhh[dd + 256];
        float b_gn = bih[dd + 512];
        float b_hn = bhh[dd + 512];
#pragma unroll
        for (int rt = 0; rt < 2; rt++) {
            int rbase = row0 + wr * 32 + rt * 16 + q * 4;
#pragma unroll
            for (int i = 0; i < 4; i++) {
                int rc = rbase + i;
                if (rc < cnt) {
                    float sr = acc_r[rt][i] + b_r;
                    float sz = acc_z[rt][i] + b_z;
                    float gn = acc_gn[rt][i] + b_gn;
                    float hn = acc_hn[rt][i] + b_hn;
                    float rg = 1.f / (1.f + __expf(-sr));
                    float zg = 1.f / (1.f + __expf(-sz));
                    float pre = gn + rg * hn;
                    float e2 = __expf(2.f * pre);
                    float ng = 1.f - 2.f / (e2 + 1.f);   // tanh(pre)
                    float xv = bf2f(Ac[(size_t)rc * 512 + 256 + dd]);
                    float h = (1.f - zg) * ng + zg * xv;
                    int v = rowidx[rc];
                    out[(size_t)v * 256 + dd] = h;
                }
            }
        }
    }
}

// ---------------- launch ----------------

extern "C" void kernel_launch(void* const* d_in, const int* in_sizes, int n_in,
                              void* d_out, int out_size, void* d_ws, size_t ws_size,
                              hipStream_t stream) {
    const float* x   = (const float*)d_in[0];
    const int*   ei  = (const int*)d_in[1];
    const float* ew  = (const float*)d_in[2];
    const int*   msk = (const int*)d_in[3];
    const float* W   = (const float*)d_in[4];
    const float* Wih = (const float*)d_in[5];
    const float* Whh = (const float*)d_in[6];
    const float* bih = (const float*)d_in[7];
    const float* bhh = (const float*)d_in[8];
    float* out = (float*)d_out;

    char* p = (char*)d_ws;
    unsigned short* Ac   = (unsigned short*)p; p += (size_t)Bn * Nn * 512 * 2;   // 32 MB
    unsigned short* Ball = (unsigned short*)p; p += (size_t)768 * 512 * 2;       // 768 KB
    int2* bucket = (int2*)p;  p += (size_t)Bn * Nn * CAP * sizeof(int2);         // 12.6 MB
    int* cnt    = (int*)p;    p += (size_t)Bn * Nn * sizeof(int);
    int* rowidx = (int*)p;    p += (size_t)Bn * Nn * sizeof(int);
    int* rowcnt = (int*)p;    p += 128;

    hipMemsetAsync(cnt, 0, (size_t)Bn * Nn * sizeof(int), stream);
    setup_kernel<<<6361, 256, 0, stream>>>(ei, msk, Wih, W, Whh, ew, cnt, bucket,
                                           rowidx, rowcnt, Ball, out);
    agg_kernel<<<8 * 512, 256, 0, stream>>>(x, cnt, bucket, rowidx, rowcnt, Ac);
    gru_kernel<<<dim3(256, 8), 512, 0, stream>>>(Ac, Ball, bih, bhh, rowidx, rowcnt, out);
}